// Round 1
// baseline (344.168 us; speedup 1.0000x reference)
//
#include <hip/hip_runtime.h>
#include <math.h>

#define Bn 32
#define Rn 512
#define Dn 256
#define Pn 5532
#define MAXU 512
#define NEGBIG -3.0e38f

// ---- workspace layout (in 4-byte words) ----
#define PROTO_OFF    0
#define PROTO_WORDS  (Bn*MAXU*Dn)                   // 4,194,304
#define COUNTS_OFF   (PROTO_OFF + PROTO_WORDS)
#define COUNTS_WORDS (Bn*Pn)                        // 177,024
#define NUNIQ_OFF    (COUNTS_OFF + COUNTS_WORDS)
#define NVALID_OFF   (NUNIQ_OFF + Bn)
#define NLL_OFF      (NVALID_OFF + 1)
#define ZERO_WORDS   (NLL_OFF + 1)                  // zero everything through here
#define CMAP_OFF     (ZERO_WORDS)
#define CCNT_OFF     (CMAP_OFF + Bn*Pn)
// total words: CCNT_OFF + Bn*MAXU  ~= 4.56M words = ~18.3 MB

// ---------------- phase 1: count labels per image ----------------
__global__ void k_count(const int* __restrict__ roi_label,
                        int* __restrict__ counts, int* __restrict__ nvalid) {
    int i = blockIdx.x * blockDim.x + threadIdx.x;   // 0..B*R
    if (i >= Bn * Rn) return;
    int b = i >> 9;                                   // /R (R=512)
    int lbl = roi_label[i] - 1;
    if (lbl >= 0) {
        atomicAdd(&counts[b * Pn + lbl], 1);
        atomicAdd(nvalid, 1);                         // coalesced per-wave by compiler
    }
}

// ---------------- phase 2: compact present pids ----------------
__global__ void k_compact(const int* __restrict__ counts, int* __restrict__ nuniq,
                          int* __restrict__ cmap, int* __restrict__ ccnt) {
    int i = blockIdx.x * blockDim.x + threadIdx.x;   // 0..B*P
    if (i >= Bn * Pn) return;
    int cnt = counts[i];
    if (cnt > 0) {
        int b = i / Pn;
        int c = atomicAdd(&nuniq[b], 1);             // compact slot (order irrelevant)
        cmap[i] = c;
        ccnt[b * MAXU + c] = cnt;
    }
}

// ---------------- phase 3: accumulate scaled features into compact slots ----------------
__global__ void k_accum(const float* __restrict__ inputs, const float* __restrict__ cls,
                        const int* __restrict__ roi_label, const int* __restrict__ cmap,
                        float* __restrict__ proto) {
    int roi = blockIdx.x;                             // 0..B*R
    int t = threadIdx.x;                              // 0..255 == D
    int b = roi >> 9;
    int lbl = roi_label[roi] - 1;
    if (lbl < 0) return;
    int c = cmap[b * Pn + lbl];
    float v = inputs[(size_t)roi * Dn + t] * cls[roi];
    atomicAdd(&proto[((size_t)(b * MAXU + c)) * Dn + t], v);
}

// ---------------- phase 4: mean + L2 normalize ----------------
__global__ void k_norm(const int* __restrict__ nuniq, const int* __restrict__ ccnt,
                       float* __restrict__ proto) {
    int slot = blockIdx.x;                            // b*MAXU + c
    int b = slot >> 9;
    int c = slot & (MAXU - 1);
    if (c >= nuniq[b]) return;
    int t = threadIdx.x;                              // 64 threads, 4 elems each
    float4 v = *(float4*)&proto[(size_t)slot * Dn + t * 4];
    float inv_cnt = 1.0f / (float)ccnt[slot];
    v.x *= inv_cnt; v.y *= inv_cnt; v.z *= inv_cnt; v.w *= inv_cnt;
    float ss = v.x*v.x + v.y*v.y + v.z*v.z + v.w*v.w;
    #pragma unroll
    for (int off = 32; off > 0; off >>= 1) ss += __shfl_xor(ss, off);
    float scale = 1.0f / fmaxf(sqrtf(ss), 1e-12f);
    v.x *= scale; v.y *= scale; v.z *= scale; v.w *= scale;
    *(float4*)&proto[(size_t)slot * Dn + t * 4] = v;
}

// ---------------- phase 5: tiled GEMM + fused online logsumexp NLL ----------------
#define TRr 64     // ROIs per block
#define TCc 128    // protos per chunk
#define KCk 64     // k per stage
#define LSTR 68    // KCk + 4 pad: keeps 16B alignment, breaks pow2 bank stride

__global__ __launch_bounds__(256) void k_loss(
    const float* __restrict__ inputs, const float* __restrict__ cls,
    const int* __restrict__ roi_label, const float* __restrict__ proto,
    const int* __restrict__ cmap, const int* __restrict__ nuniq,
    float* __restrict__ nll_sum)
{
    __shared__ __align__(16) float xs[TRr * LSTR];    // 17.4 KB
    __shared__ __align__(16) float ps[TCc * LSTR];    // 34.8 KB
    __shared__ float m_run[TRr], s_run[TRr], dlbl[TRr], clsv[TRr];
    __shared__ int lblc[TRr];

    const int t  = threadIdx.x;
    const int tx = t & 15;          // proto dim: protos tx + 16*i, i<8
    const int ty = t >> 4;          // roi dim:   rois   ty + 16*j, j<4
    const int b = blockIdx.y;
    const int roiBase = blockIdx.x * TRr;
    const int U = nuniq[b];

    if (t < TRr) {
        m_run[t] = NEGBIG; s_run[t] = 0.f; dlbl[t] = 0.f;
        clsv[t] = cls[b * Rn + roiBase + t];
        int lbl = roi_label[b * Rn + roiBase + t] - 1;
        lblc[t] = (lbl >= 0) ? cmap[b * Pn + lbl] : -1;
    }
    __syncthreads();

    const int nchunks = (U + TCc - 1) / TCc;          // <= 4
    for (int pc = 0; pc < nchunks; ++pc) {
        float acc[4][8];
        #pragma unroll
        for (int j = 0; j < 4; ++j)
            #pragma unroll
            for (int i = 0; i < 8; ++i) acc[j][i] = 0.f;

        for (int kc = 0; kc < Dn / KCk; ++kc) {
            // stage x chunk: 64 rows x 16 float4 (scaled by cls)
            #pragma unroll
            for (int s2 = 0; s2 < 4; ++s2) {
                int idx = t + 256 * s2;
                int rr = idx >> 4, f4 = idx & 15;
                float4 v = *(const float4*)&inputs[(size_t)(b*Rn + roiBase + rr) * Dn + kc*KCk + f4*4];
                float cw = clsv[rr];
                v.x *= cw; v.y *= cw; v.z *= cw; v.w *= cw;
                *(float4*)&xs[rr * LSTR + f4 * 4] = v;
            }
            // stage proto chunk: 128 rows x 16 float4 (rows >= U are zeros)
            #pragma unroll
            for (int s2 = 0; s2 < 8; ++s2) {
                int idx = t + 256 * s2;
                int rr = idx >> 4, f4 = idx & 15;
                float4 v = *(const float4*)&proto[(size_t)(b*MAXU + pc*TCc + rr) * Dn + kc*KCk + f4*4];
                *(float4*)&ps[rr * LSTR + f4 * 4] = v;
            }
            __syncthreads();

            #pragma unroll 2
            for (int kk = 0; kk < KCk; kk += 4) {
                float4 xv[4], pv[8];
                #pragma unroll
                for (int j = 0; j < 4; ++j) xv[j] = *(const float4*)&xs[(ty + 16*j) * LSTR + kk];
                #pragma unroll
                for (int i = 0; i < 8; ++i) pv[i] = *(const float4*)&ps[(tx + 16*i) * LSTR + kk];
                #pragma unroll
                for (int j = 0; j < 4; ++j)
                    #pragma unroll
                    for (int i = 0; i < 8; ++i) {
                        acc[j][i] = fmaf(xv[j].x, pv[i].x, acc[j][i]);
                        acc[j][i] = fmaf(xv[j].y, pv[i].y, acc[j][i]);
                        acc[j][i] = fmaf(xv[j].z, pv[i].z, acc[j][i]);
                        acc[j][i] = fmaf(xv[j].w, pv[i].w, acc[j][i]);
                    }
            }
            __syncthreads();
        }

        // masked online logsumexp for this proto chunk
        #pragma unroll
        for (int j = 0; j < 4; ++j) {
            int rr = ty + 16 * j;
            int lc = lblc[rr];
            float m = NEGBIG, s = 0.f;
            #pragma unroll
            for (int i = 0; i < 8; ++i) {
                int c = pc * TCc + tx + 16 * i;
                if (c < U) {
                    float d = acc[j][i];
                    if (c == lc) dlbl[rr] = d;         // unique writer per rr
                    if (d > m) { s = s * __expf(m - d) + 1.0f; m = d; }
                    else       { s += __expf(d - m); }
                }
            }
            // reduce across the 16 tx lanes (NEGBIG-safe: exp(0)*0 contributions)
            #pragma unroll
            for (int off = 1; off < 16; off <<= 1) {
                float om = __shfl_xor(m, off);
                float os = __shfl_xor(s, off);
                float M = fmaxf(m, om);
                s = s * __expf(m - M) + os * __expf(om - M);
                m = M;
            }
            if (tx == 0) {   // merge into running state; same thread owns rr every chunk
                float mr = m_run[rr], sr = s_run[rr];
                float M = fmaxf(mr, m);
                s_run[rr] = sr * __expf(mr - M) + s * __expf(m - M);
                m_run[rr] = M;
            }
        }
        __syncthreads();
    }

    // final per-ROI NLL, block sum, one atomic
    if (t < TRr) {
        float v = 0.f;
        if (lblc[t] >= 0) v = m_run[t] + __logf(s_run[t]) - dlbl[t];
        #pragma unroll
        for (int off = 1; off < 64; off <<= 1) v += __shfl_xor(v, off);
        if (t == 0) atomicAdd(nll_sum, v);
    }
}

// ---------------- phase 6: finalize ----------------
__global__ void k_final(const float* __restrict__ nll_sum,
                        const int* __restrict__ nvalid, float* __restrict__ out) {
    out[0] = nll_sum[0] / fmaxf((float)nvalid[0], 1.0f);
}

extern "C" void kernel_launch(void* const* d_in, const int* in_sizes, int n_in,
                              void* d_out, int out_size, void* d_ws, size_t ws_size,
                              hipStream_t stream) {
    const float* inputs = (const float*)d_in[0];
    const float* cls    = (const float*)d_in[1];
    const int*   roi    = (const int*)d_in[2];
    float* out = (float*)d_out;

    float* wsf = (float*)d_ws;
    int*   wsi = (int*)d_ws;
    float* proto  = wsf + PROTO_OFF;
    int*   counts = wsi + COUNTS_OFF;
    int*   nuniq  = wsi + NUNIQ_OFF;
    int*   nvalid = wsi + NVALID_OFF;
    float* nll    = wsf + NLL_OFF;
    int*   cmap   = wsi + CMAP_OFF;
    int*   ccnt   = wsi + CCNT_OFF;

    hipMemsetAsync(d_ws, 0, (size_t)ZERO_WORDS * 4, stream);
    k_count  <<<(Bn*Rn)/256, 256, 0, stream>>>(roi, counts, nvalid);
    k_compact<<<(Bn*Pn + 255)/256, 256, 0, stream>>>(counts, nuniq, cmap, ccnt);
    k_accum  <<<Bn*Rn, Dn, 0, stream>>>(inputs, cls, roi, cmap, proto);
    k_norm   <<<Bn*MAXU, 64, 0, stream>>>(nuniq, ccnt, proto);
    dim3 g(Rn / TRr, Bn);
    k_loss   <<<g, 256, 0, stream>>>(inputs, cls, roi, proto, cmap, nuniq, nll);
    k_final  <<<1, 1, 0, stream>>>(nll, nvalid, out);
}

// Round 2
// 208.007 us; speedup vs baseline: 1.6546x; 1.6546x over previous
//
#include <hip/hip_runtime.h>
#include <math.h>

#define Bn 32
#define Rn 512
#define Dn 256
#define Pn 5532
#define MAXU 512
#define NEGBIG -3.0e38f

// ---- workspace layout (in 4-byte words) ----
#define PROTO_OFF    0
#define PROTO_WORDS  (Bn*MAXU*Dn)                   // 4,194,304
#define COUNTS_OFF   (PROTO_OFF + PROTO_WORDS)
#define COUNTS_WORDS (Bn*Pn)                        // 177,024
#define NUNIQ_OFF    (COUNTS_OFF + COUNTS_WORDS)
#define NVALID_OFF   (NUNIQ_OFF + Bn)               // 32-entry per-image valid count
#define NLL_OFF      (NVALID_OFF + Bn)
#define ZERO_WORDS   (NLL_OFF + 1)                  // zero everything through here
#define CMAP_OFF     (ZERO_WORDS)
#define CCNT_OFF     (CMAP_OFF + Bn*Pn)
// total words: CCNT_OFF + Bn*MAXU  ~= 4.56M words = ~18.3 MB

// ---------------- phase 1: count labels per image ----------------
__global__ void k_count(const int* __restrict__ roi_label,
                        int* __restrict__ counts) {
    int i = blockIdx.x * blockDim.x + threadIdx.x;   // 0..B*R
    if (i >= Bn * Rn) return;
    int b = i >> 9;                                   // /R (R=512)
    int lbl = roi_label[i] - 1;
    if (lbl >= 0) atomicAdd(&counts[b * Pn + lbl], 1);  // ~1.07 hits/addr: low contention
}

// ---------------- phase 2: compact present pids via block scan (NO atomics) ----------------
// one block per image; slot order deterministic (ascending pid) — order is
// irrelevant anyway since logsumexp is permutation-invariant.
__global__ __launch_bounds__(1024) void k_compact(
    const int* __restrict__ counts, int* __restrict__ nuniq,
    int* __restrict__ cmap, int* __restrict__ ccnt,
    int* __restrict__ nvalid_arr) {
    const int b = blockIdx.x;
    const int t = threadIdx.x;
    const int lane = t & 63, wid = t >> 6;            // 16 waves
    __shared__ int warp_off[16];
    __shared__ int wsum[16];
    int base = 0;                                     // replicated in every thread
    int my_valid = 0;
    for (int i0 = 0; i0 < Pn; i0 += 1024) {
        int i = i0 + t;
        int cnt = (i < Pn) ? counts[b * Pn + i] : 0;
        my_valid += cnt;
        unsigned long long mask = __ballot(cnt > 0);
        int prefix = __popcll(mask & ((1ULL << lane) - 1ULL));
        if (lane == 0) warp_off[wid] = __popcll(mask);
        __syncthreads();
        int woff = 0, tot = 0;
        #pragma unroll
        for (int w = 0; w < 16; ++w) {
            int v = warp_off[w];
            if (w < wid) woff += v;
            tot += v;
        }
        if (cnt > 0) {
            int c = base + woff + prefix;             // < MAXU (<=512 present/image)
            cmap[b * Pn + i] = c;
            ccnt[b * MAXU + c] = cnt;
        }
        base += tot;                                  // identical in all threads
        __syncthreads();                              // protect warp_off reuse
    }
    #pragma unroll
    for (int off = 32; off > 0; off >>= 1) my_valid += __shfl_xor(my_valid, off);
    if (lane == 0) wsum[wid] = my_valid;
    __syncthreads();
    if (t == 0) {
        int s = 0;
        #pragma unroll
        for (int w = 0; w < 16; ++w) s += wsum[w];
        nvalid_arr[b] = s;
        nuniq[b] = base;
    }
}

// ---------------- phase 3: accumulate scaled features into compact slots ----------------
__global__ void k_accum(const float* __restrict__ inputs, const float* __restrict__ cls,
                        const int* __restrict__ roi_label, const int* __restrict__ cmap,
                        float* __restrict__ proto) {
    int roi = blockIdx.x;                             // 0..B*R
    int t = threadIdx.x;                              // 0..255 == D
    int b = roi >> 9;
    int lbl = roi_label[roi] - 1;
    if (lbl < 0) return;
    int c = cmap[b * Pn + lbl];
    float v = inputs[(size_t)roi * Dn + t] * cls[roi];
    atomicAdd(&proto[((size_t)(b * MAXU + c)) * Dn + t], v);
}

// ---------------- phase 4: mean + L2 normalize ----------------
__global__ void k_norm(const int* __restrict__ nuniq, const int* __restrict__ ccnt,
                       float* __restrict__ proto) {
    int slot = blockIdx.x;                            // b*MAXU + c
    int b = slot >> 9;
    int c = slot & (MAXU - 1);
    if (c >= nuniq[b]) return;
    int t = threadIdx.x;                              // 64 threads, 4 elems each
    float4 v = *(float4*)&proto[(size_t)slot * Dn + t * 4];
    float inv_cnt = 1.0f / (float)ccnt[slot];
    v.x *= inv_cnt; v.y *= inv_cnt; v.z *= inv_cnt; v.w *= inv_cnt;
    float ss = v.x*v.x + v.y*v.y + v.z*v.z + v.w*v.w;
    #pragma unroll
    for (int off = 32; off > 0; off >>= 1) ss += __shfl_xor(ss, off);
    float scale = 1.0f / fmaxf(sqrtf(ss), 1e-12f);
    v.x *= scale; v.y *= scale; v.z *= scale; v.w *= scale;
    *(float4*)&proto[(size_t)slot * Dn + t * 4] = v;
}

// ---------------- phase 5: tiled GEMM + fused online logsumexp NLL ----------------
#define TRr 64     // ROIs per block
#define TCc 128    // protos per chunk
#define KCk 64     // k per stage
#define LSTR 68    // KCk + 4 pad: keeps 16B alignment, breaks pow2 bank stride

__global__ __launch_bounds__(256) void k_loss(
    const float* __restrict__ inputs, const float* __restrict__ cls,
    const int* __restrict__ roi_label, const float* __restrict__ proto,
    const int* __restrict__ cmap, const int* __restrict__ nuniq,
    float* __restrict__ nll_sum)
{
    __shared__ __align__(16) float xs[TRr * LSTR];    // 17.4 KB
    __shared__ __align__(16) float ps[TCc * LSTR];    // 34.8 KB
    __shared__ float m_run[TRr], s_run[TRr], dlbl[TRr], clsv[TRr];
    __shared__ int lblc[TRr];

    const int t  = threadIdx.x;
    const int tx = t & 15;          // proto dim: protos tx + 16*i, i<8
    const int ty = t >> 4;          // roi dim:   rois   ty + 16*j, j<4
    const int b = blockIdx.y;
    const int roiBase = blockIdx.x * TRr;
    const int U = nuniq[b];

    if (t < TRr) {
        m_run[t] = NEGBIG; s_run[t] = 0.f; dlbl[t] = 0.f;
        clsv[t] = cls[b * Rn + roiBase + t];
        int lbl = roi_label[b * Rn + roiBase + t] - 1;
        lblc[t] = (lbl >= 0) ? cmap[b * Pn + lbl] : -1;
    }
    __syncthreads();

    const int nchunks = (U + TCc - 1) / TCc;          // <= 4
    for (int pc = 0; pc < nchunks; ++pc) {
        float acc[4][8];
        #pragma unroll
        for (int j = 0; j < 4; ++j)
            #pragma unroll
            for (int i = 0; i < 8; ++i) acc[j][i] = 0.f;

        for (int kc = 0; kc < Dn / KCk; ++kc) {
            // stage x chunk: 64 rows x 16 float4 (scaled by cls)
            #pragma unroll
            for (int s2 = 0; s2 < 4; ++s2) {
                int idx = t + 256 * s2;
                int rr = idx >> 4, f4 = idx & 15;
                float4 v = *(const float4*)&inputs[(size_t)(b*Rn + roiBase + rr) * Dn + kc*KCk + f4*4];
                float cw = clsv[rr];
                v.x *= cw; v.y *= cw; v.z *= cw; v.w *= cw;
                *(float4*)&xs[rr * LSTR + f4 * 4] = v;
            }
            // stage proto chunk: 128 rows x 16 float4 (rows >= U are zeros)
            #pragma unroll
            for (int s2 = 0; s2 < 8; ++s2) {
                int idx = t + 256 * s2;
                int rr = idx >> 4, f4 = idx & 15;
                float4 v = *(const float4*)&proto[(size_t)(b*MAXU + pc*TCc + rr) * Dn + kc*KCk + f4*4];
                *(float4*)&ps[rr * LSTR + f4 * 4] = v;
            }
            __syncthreads();

            #pragma unroll 2
            for (int kk = 0; kk < KCk; kk += 4) {
                float4 xv[4], pv[8];
                #pragma unroll
                for (int j = 0; j < 4; ++j) xv[j] = *(const float4*)&xs[(ty + 16*j) * LSTR + kk];
                #pragma unroll
                for (int i = 0; i < 8; ++i) pv[i] = *(const float4*)&ps[(tx + 16*i) * LSTR + kk];
                #pragma unroll
                for (int j = 0; j < 4; ++j)
                    #pragma unroll
                    for (int i = 0; i < 8; ++i) {
                        acc[j][i] = fmaf(xv[j].x, pv[i].x, acc[j][i]);
                        acc[j][i] = fmaf(xv[j].y, pv[i].y, acc[j][i]);
                        acc[j][i] = fmaf(xv[j].z, pv[i].z, acc[j][i]);
                        acc[j][i] = fmaf(xv[j].w, pv[i].w, acc[j][i]);
                    }
            }
            __syncthreads();
        }

        // masked online logsumexp for this proto chunk
        #pragma unroll
        for (int j = 0; j < 4; ++j) {
            int rr = ty + 16 * j;
            int lc = lblc[rr];
            float m = NEGBIG, s = 0.f;
            #pragma unroll
            for (int i = 0; i < 8; ++i) {
                int c = pc * TCc + tx + 16 * i;
                if (c < U) {
                    float d = acc[j][i];
                    if (c == lc) dlbl[rr] = d;         // unique writer per rr
                    if (d > m) { s = s * __expf(m - d) + 1.0f; m = d; }
                    else       { s += __expf(d - m); }
                }
            }
            // reduce across the 16 tx lanes (NEGBIG-safe: exp(0)*0 contributions)
            #pragma unroll
            for (int off = 1; off < 16; off <<= 1) {
                float om = __shfl_xor(m, off);
                float os = __shfl_xor(s, off);
                float M = fmaxf(m, om);
                s = s * __expf(m - M) + os * __expf(om - M);
                m = M;
            }
            if (tx == 0) {   // merge into running state; same thread owns rr every chunk
                float mr = m_run[rr], sr = s_run[rr];
                float M = fmaxf(mr, m);
                s_run[rr] = sr * __expf(mr - M) + s * __expf(m - M);
                m_run[rr] = M;
            }
        }
        __syncthreads();
    }

    // final per-ROI NLL, block sum, one atomic
    if (t < TRr) {
        float v = 0.f;
        if (lblc[t] >= 0) v = m_run[t] + __logf(s_run[t]) - dlbl[t];
        #pragma unroll
        for (int off = 1; off < 64; off <<= 1) v += __shfl_xor(v, off);
        if (t == 0) atomicAdd(nll_sum, v);
    }
}

// ---------------- phase 6: finalize ----------------
__global__ void k_final(const float* __restrict__ nll_sum,
                        const int* __restrict__ nvalid_arr, float* __restrict__ out) {
    int s = 0;
    #pragma unroll
    for (int b = 0; b < Bn; ++b) s += nvalid_arr[b];
    out[0] = nll_sum[0] / fmaxf((float)s, 1.0f);
}

extern "C" void kernel_launch(void* const* d_in, const int* in_sizes, int n_in,
                              void* d_out, int out_size, void* d_ws, size_t ws_size,
                              hipStream_t stream) {
    const float* inputs = (const float*)d_in[0];
    const float* cls    = (const float*)d_in[1];
    const int*   roi    = (const int*)d_in[2];
    float* out = (float*)d_out;

    float* wsf = (float*)d_ws;
    int*   wsi = (int*)d_ws;
    float* proto  = wsf + PROTO_OFF;
    int*   counts = wsi + COUNTS_OFF;
    int*   nuniq  = wsi + NUNIQ_OFF;
    int*   nvalid = wsi + NVALID_OFF;
    float* nll    = wsf + NLL_OFF;
    int*   cmap   = wsi + CMAP_OFF;
    int*   ccnt   = wsi + CCNT_OFF;

    hipMemsetAsync(d_ws, 0, (size_t)ZERO_WORDS * 4, stream);
    k_count  <<<(Bn*Rn)/256, 256, 0, stream>>>(roi, counts);
    k_compact<<<Bn, 1024, 0, stream>>>(counts, nuniq, cmap, ccnt, nvalid);
    k_accum  <<<Bn*Rn, Dn, 0, stream>>>(inputs, cls, roi, cmap, proto);
    k_norm   <<<Bn*MAXU, 64, 0, stream>>>(nuniq, ccnt, proto);
    dim3 g(Rn / TRr, Bn);
    k_loss   <<<g, 256, 0, stream>>>(inputs, cls, roi, proto, cmap, nuniq, nll);
    k_final  <<<1, 1, 0, stream>>>(nll, nvalid, out);
}

// Round 3
// 169.434 us; speedup vs baseline: 2.0313x; 1.2277x over previous
//
#include <hip/hip_runtime.h>
#include <math.h>

#define Bn 32
#define Rn 512
#define Dn 256
#define Pn 5532
#define MAXU 512
#define NEGBIG -3.0e38f

// ---- workspace layout (in 4-byte words) ----
#define PROTO_OFF    0
#define PROTO_WORDS  (Bn*MAXU*Dn)                   // 4,194,304
#define COUNTS_OFF   (PROTO_OFF + PROTO_WORDS)
#define COUNTS_WORDS (Bn*Pn)                        // 177,024
#define NUNIQ_OFF    (COUNTS_OFF + COUNTS_WORDS)
#define NVALID_OFF   (NUNIQ_OFF + Bn)               // 32-entry per-image valid count
#define NLL_OFF      (NVALID_OFF + Bn)
#define ZERO_WORDS   (NLL_OFF + 1)                  // zero everything through here
#define CMAP_OFF     (ZERO_WORDS)
#define CCNT_OFF     (CMAP_OFF + Bn*Pn)
#define MPART_OFF    (CCNT_OFF + Bn*MAXU)           // B*R*4 chunk maxes
#define SPART_OFF    (MPART_OFF + Bn*Rn*4)          // B*R*4 chunk sums
#define DLBL_OFF     (SPART_OFF + Bn*Rn*4)          // B*R own-label dots
// total words: DLBL_OFF + Bn*Rn ~= 4.71M words ~= 18.9 MB

// ---------------- phase 1: count labels per image ----------------
__global__ void k_count(const int* __restrict__ roi_label,
                        int* __restrict__ counts) {
    int i = blockIdx.x * blockDim.x + threadIdx.x;   // 0..B*R
    if (i >= Bn * Rn) return;
    int b = i >> 9;                                   // /R (R=512)
    int lbl = roi_label[i] - 1;
    if (lbl >= 0) atomicAdd(&counts[b * Pn + lbl], 1);  // ~1.07 hits/addr: low contention
}

// ---------------- phase 2: compact present pids via block scan (NO atomics) ----------------
__global__ __launch_bounds__(1024) void k_compact(
    const int* __restrict__ counts, int* __restrict__ nuniq,
    int* __restrict__ cmap, int* __restrict__ ccnt,
    int* __restrict__ nvalid_arr) {
    const int b = blockIdx.x;
    const int t = threadIdx.x;
    const int lane = t & 63, wid = t >> 6;            // 16 waves
    __shared__ int warp_off[16];
    __shared__ int wsum[16];
    int base = 0;                                     // replicated in every thread
    int my_valid = 0;
    for (int i0 = 0; i0 < Pn; i0 += 1024) {
        int i = i0 + t;
        int cnt = (i < Pn) ? counts[b * Pn + i] : 0;
        my_valid += cnt;
        unsigned long long mask = __ballot(cnt > 0);
        int prefix = __popcll(mask & ((1ULL << lane) - 1ULL));
        if (lane == 0) warp_off[wid] = __popcll(mask);
        __syncthreads();
        int woff = 0, tot = 0;
        #pragma unroll
        for (int w = 0; w < 16; ++w) {
            int v = warp_off[w];
            if (w < wid) woff += v;
            tot += v;
        }
        if (cnt > 0) {
            int c = base + woff + prefix;             // < MAXU (<=512 present/image)
            cmap[b * Pn + i] = c;
            ccnt[b * MAXU + c] = cnt;
        }
        base += tot;                                  // identical in all threads
        __syncthreads();                              // protect warp_off reuse
    }
    #pragma unroll
    for (int off = 32; off > 0; off >>= 1) my_valid += __shfl_xor(my_valid, off);
    if (lane == 0) wsum[wid] = my_valid;
    __syncthreads();
    if (t == 0) {
        int s = 0;
        #pragma unroll
        for (int w = 0; w < 16; ++w) s += wsum[w];
        nvalid_arr[b] = s;
        nuniq[b] = base;
    }
}

// ---------------- phase 3: accumulate scaled features into compact slots ----------------
__global__ void k_accum(const float* __restrict__ inputs, const float* __restrict__ cls,
                        const int* __restrict__ roi_label, const int* __restrict__ cmap,
                        float* __restrict__ proto) {
    int roi = blockIdx.x;                             // 0..B*R
    int t = threadIdx.x;                              // 0..255 == D
    int b = roi >> 9;
    int lbl = roi_label[roi] - 1;
    if (lbl < 0) return;
    int c = cmap[b * Pn + lbl];
    float v = inputs[(size_t)roi * Dn + t] * cls[roi];
    atomicAdd(&proto[((size_t)(b * MAXU + c)) * Dn + t], v);
}

// ---------------- phase 4: mean + L2 normalize ----------------
__global__ void k_norm(const int* __restrict__ nuniq, const int* __restrict__ ccnt,
                       float* __restrict__ proto) {
    int slot = blockIdx.x;                            // b*MAXU + c
    int b = slot >> 9;
    int c = slot & (MAXU - 1);
    if (c >= nuniq[b]) return;
    int t = threadIdx.x;                              // 64 threads, 4 elems each
    float4 v = *(float4*)&proto[(size_t)slot * Dn + t * 4];
    float inv_cnt = 1.0f / (float)ccnt[slot];
    v.x *= inv_cnt; v.y *= inv_cnt; v.z *= inv_cnt; v.w *= inv_cnt;
    float ss = v.x*v.x + v.y*v.y + v.z*v.z + v.w*v.w;
    #pragma unroll
    for (int off = 32; off > 0; off >>= 1) ss += __shfl_xor(ss, off);
    float scale = 1.0f / fmaxf(sqrtf(ss), 1e-12f);
    v.x *= scale; v.y *= scale; v.z *= scale; v.w *= scale;
    *(float4*)&proto[(size_t)slot * Dn + t * 4] = v;
}

// ---------------- phase 5: chunk-split tiled GEMM + per-chunk logsumexp ----------------
// grid (rt=8, pc=4, b=32) = 1024 blocks -> 4 blocks/CU resident (LDS 28.2KB, 5 fit)
#define TRr 64     // ROIs per block
#define TCc 128    // protos per block (one chunk)
#define KCk 32     // k per stage
#define LSTR 36    // KCk + 4 pad: same mod-32 bank residue as 68 (measured 0 conflicts)

__global__ __launch_bounds__(256) void k_loss(
    const float* __restrict__ inputs, const float* __restrict__ cls,
    const int* __restrict__ roi_label, const float* __restrict__ proto,
    const int* __restrict__ cmap, const int* __restrict__ nuniq,
    float* __restrict__ mpart, float* __restrict__ spart,
    float* __restrict__ dlbl_arr)
{
    __shared__ __align__(16) float xs[TRr * LSTR];    // 9.2 KB
    __shared__ __align__(16) float ps[TCc * LSTR];    // 18.4 KB
    __shared__ float clsv[TRr];
    __shared__ int lblc[TRr];

    const int t  = threadIdx.x;
    const int tx = t & 15;          // proto dim: protos tx + 16*i, i<8
    const int ty = t >> 4;          // roi dim:   rois   ty + 16*j, j<4
    const int b = blockIdx.z;
    const int pc = blockIdx.y;
    const int roiBase = blockIdx.x * TRr;
    const int U = nuniq[b];
    if (pc * TCc >= U) return;                        // whole block exits together

    if (t < TRr) {
        clsv[t] = cls[b * Rn + roiBase + t];
        int lbl = roi_label[b * Rn + roiBase + t] - 1;
        lblc[t] = (lbl >= 0) ? cmap[b * Pn + lbl] : -1;
    }
    __syncthreads();

    float acc[4][8];
    #pragma unroll
    for (int j = 0; j < 4; ++j)
        #pragma unroll
        for (int i = 0; i < 8; ++i) acc[j][i] = 0.f;

    for (int kc = 0; kc < Dn / KCk; ++kc) {           // 8 stages
        // stage x chunk: 64 rows x 8 float4 (scaled by cls)
        #pragma unroll
        for (int s2 = 0; s2 < 2; ++s2) {
            int idx = t + 256 * s2;
            int rr = idx >> 3, f4 = idx & 7;
            float4 v = *(const float4*)&inputs[(size_t)(b*Rn + roiBase + rr) * Dn + kc*KCk + f4*4];
            float cw = clsv[rr];
            v.x *= cw; v.y *= cw; v.z *= cw; v.w *= cw;
            *(float4*)&xs[rr * LSTR + f4 * 4] = v;
        }
        // stage proto chunk: 128 rows x 8 float4 (rows >= U are zeros)
        #pragma unroll
        for (int s2 = 0; s2 < 4; ++s2) {
            int idx = t + 256 * s2;
            int rr = idx >> 3, f4 = idx & 7;
            float4 v = *(const float4*)&proto[(size_t)(b*MAXU + pc*TCc + rr) * Dn + kc*KCk + f4*4];
            *(float4*)&ps[rr * LSTR + f4 * 4] = v;
        }
        __syncthreads();

        #pragma unroll 2
        for (int kk = 0; kk < KCk; kk += 4) {
            float4 xv[4], pv[8];
            #pragma unroll
            for (int j = 0; j < 4; ++j) xv[j] = *(const float4*)&xs[(ty + 16*j) * LSTR + kk];
            #pragma unroll
            for (int i = 0; i < 8; ++i) pv[i] = *(const float4*)&ps[(tx + 16*i) * LSTR + kk];
            #pragma unroll
            for (int j = 0; j < 4; ++j)
                #pragma unroll
                for (int i = 0; i < 8; ++i) {
                    acc[j][i] = fmaf(xv[j].x, pv[i].x, acc[j][i]);
                    acc[j][i] = fmaf(xv[j].y, pv[i].y, acc[j][i]);
                    acc[j][i] = fmaf(xv[j].z, pv[i].z, acc[j][i]);
                    acc[j][i] = fmaf(xv[j].w, pv[i].w, acc[j][i]);
                }
        }
        __syncthreads();
    }

    // per-chunk masked logsumexp; write partials (one writer per location)
    #pragma unroll
    for (int j = 0; j < 4; ++j) {
        int rr = ty + 16 * j;
        int lc = lblc[rr];
        float m = NEGBIG, s = 0.f;
        #pragma unroll
        for (int i = 0; i < 8; ++i) {
            int c = pc * TCc + tx + 16 * i;
            if (c < U) {
                float d = acc[j][i];
                if (c == lc) dlbl_arr[b * Rn + roiBase + rr] = d;  // exactly one writer over all blocks
                if (d > m) { s = s * __expf(m - d) + 1.0f; m = d; }
                else       { s += __expf(d - m); }
            }
        }
        #pragma unroll
        for (int off = 1; off < 16; off <<= 1) {
            float om = __shfl_xor(m, off);
            float os = __shfl_xor(s, off);
            float M = fmaxf(m, om);
            s = s * __expf(m - M) + os * __expf(om - M);
            m = M;
        }
        if (tx == 0) {
            int roi = b * Rn + roiBase + rr;
            mpart[roi * 4 + pc] = m;
            spart[roi * 4 + pc] = s;
        }
    }
}

// ---------------- phase 5b: merge chunk partials -> NLL sum ----------------
__global__ __launch_bounds__(256) void k_merge(
    const int* __restrict__ roi_label, const int* __restrict__ nuniq,
    const float* __restrict__ mpart, const float* __restrict__ spart,
    const float* __restrict__ dlbl_arr, float* __restrict__ nll_sum)
{
    __shared__ float wsum[4];
    int roi = blockIdx.x * 256 + threadIdx.x;         // 0..16383
    int b = roi >> 9;
    int lbl = roi_label[roi] - 1;
    float v = 0.f;
    if (lbl >= 0) {
        int U = nuniq[b];
        int nch = (U + TCc - 1) / TCc;
        float m = NEGBIG, s = 0.f;
        for (int pc = 0; pc < nch; ++pc) {
            float om = mpart[roi * 4 + pc], os = spart[roi * 4 + pc];
            float M = fmaxf(m, om);
            s = s * __expf(m - M) + os * __expf(om - M);
            m = M;
        }
        v = m + __logf(s) - dlbl_arr[roi];
    }
    #pragma unroll
    for (int off = 1; off < 64; off <<= 1) v += __shfl_xor(v, off);
    int lane = threadIdx.x & 63, wid = threadIdx.x >> 6;
    if (lane == 0) wsum[wid] = v;
    __syncthreads();
    if (threadIdx.x == 0)
        atomicAdd(nll_sum, wsum[0] + wsum[1] + wsum[2] + wsum[3]);
}

// ---------------- phase 6: finalize ----------------
__global__ void k_final(const float* __restrict__ nll_sum,
                        const int* __restrict__ nvalid_arr, float* __restrict__ out) {
    int s = 0;
    #pragma unroll
    for (int b = 0; b < Bn; ++b) s += nvalid_arr[b];
    out[0] = nll_sum[0] / fmaxf((float)s, 1.0f);
}

extern "C" void kernel_launch(void* const* d_in, const int* in_sizes, int n_in,
                              void* d_out, int out_size, void* d_ws, size_t ws_size,
                              hipStream_t stream) {
    const float* inputs = (const float*)d_in[0];
    const float* cls    = (const float*)d_in[1];
    const int*   roi    = (const int*)d_in[2];
    float* out = (float*)d_out;

    float* wsf = (float*)d_ws;
    int*   wsi = (int*)d_ws;
    float* proto  = wsf + PROTO_OFF;
    int*   counts = wsi + COUNTS_OFF;
    int*   nuniq  = wsi + NUNIQ_OFF;
    int*   nvalid = wsi + NVALID_OFF;
    float* nll    = wsf + NLL_OFF;
    int*   cmap   = wsi + CMAP_OFF;
    int*   ccnt   = wsi + CCNT_OFF;
    float* mpart  = wsf + MPART_OFF;
    float* spart  = wsf + SPART_OFF;
    float* dlbl   = wsf + DLBL_OFF;

    hipMemsetAsync(d_ws, 0, (size_t)ZERO_WORDS * 4, stream);
    k_count  <<<(Bn*Rn)/256, 256, 0, stream>>>(roi, counts);
    k_compact<<<Bn, 1024, 0, stream>>>(counts, nuniq, cmap, ccnt, nvalid);
    k_accum  <<<Bn*Rn, Dn, 0, stream>>>(inputs, cls, roi, cmap, proto);
    k_norm   <<<Bn*MAXU, 64, 0, stream>>>(nuniq, ccnt, proto);
    dim3 g(Rn / TRr, 4, Bn);
    k_loss   <<<g, 256, 0, stream>>>(inputs, cls, roi, proto, cmap, nuniq, mpart, spart, dlbl);
    k_merge  <<<(Bn*Rn)/256, 256, 0, stream>>>(roi, nuniq, mpart, spart, dlbl, nll);
    k_final  <<<1, 1, 0, stream>>>(nll, nvalid, out);
}

// Round 4
// 135.338 us; speedup vs baseline: 2.5430x; 1.2519x over previous
//
#include <hip/hip_runtime.h>
#include <math.h>

#define Bn 32
#define Rn 512
#define Dn 256
#define Pn 5532
#define MAXU 512
#define NEGBIG -3.0e38f

typedef short short8 __attribute__((ext_vector_type(8)));
typedef float floatx4 __attribute__((ext_vector_type(4)));

// ---- workspace layout (4-byte words). Only [0, ZERO_WORDS) is memset. ----
#define COUNTS_OFF   0
#define NLL_OFF      (Bn*Pn)
#define ZERO_WORDS   (NLL_OFF + 1)                  // 708 KB zeroed per call
#define PROTO_OFF    ZERO_WORDS
#define CMAP_OFF     (PROTO_OFF + Bn*MAXU*Dn)
#define CCNT_OFF     (CMAP_OFF + Bn*Pn)
#define CURS_OFF     (CCNT_OFF + Bn*MAXU)           // start offsets, k_fill bumps to end
#define RLIST_OFF    (CURS_OFF + Bn*MAXU)
#define NUNIQ_OFF    (RLIST_OFF + Bn*Rn)
#define NVALID_OFF   (NUNIQ_OFF + Bn)
#define MPART_OFF    (NVALID_OFF + Bn)
#define SPART_OFF    (MPART_OFF + Bn*Rn*4)
#define DLBL_OFF     (SPART_OFF + Bn*Rn*4)
// end = DLBL_OFF + Bn*Rn  ~= 4.75M words ~= 19.0 MB

__device__ inline unsigned short bf16r(float f) {   // fp32 -> bf16 RNE
    union { float f; unsigned int u; } c; c.f = f;
    return (unsigned short)((c.u + 0x7FFFu + ((c.u >> 16) & 1u)) >> 16);
}
__device__ inline float bf16tof(unsigned short h) {
    union { unsigned int u; float f; } c; c.u = ((unsigned int)h) << 16;
    return c.f;
}

// ---------------- phase 1: count labels per image ----------------
__global__ void k_count(const int* __restrict__ roi_label,
                        int* __restrict__ counts) {
    int i = blockIdx.x * blockDim.x + threadIdx.x;
    if (i >= Bn * Rn) return;
    int b = i >> 9;
    int lbl = roi_label[i] - 1;
    if (lbl >= 0) atomicAdd(&counts[b * Pn + lbl], 1);
}

// ---------------- phase 2: compact slots + CSR offsets via block scans ----------------
__global__ __launch_bounds__(1024) void k_compact(
    const int* __restrict__ counts, int* __restrict__ nuniq,
    int* __restrict__ cmap, int* __restrict__ ccnt,
    int* __restrict__ cursor, int* __restrict__ nvalid_arr) {
    const int b = blockIdx.x;
    const int t = threadIdx.x;
    const int lane = t & 63, wid = t >> 6;            // 16 waves
    __shared__ int wpres[16], wcnt[16];
    int basePres = 0, baseCnt = 0;                    // replicated
    for (int i0 = 0; i0 < Pn; i0 += 1024) {
        int i = i0 + t;
        int cnt = (i < Pn) ? counts[b * Pn + i] : 0;
        bool pres = cnt > 0;
        unsigned long long mask = __ballot(pres);
        int pfx_pres = __popcll(mask & ((1ULL << lane) - 1ULL));
        // wave inclusive scan of cnt
        int v = cnt;
        #pragma unroll
        for (int off = 1; off < 64; off <<= 1) {
            int u = __shfl_up(v, off);
            if (lane >= off) v += u;
        }
        int pfx_cnt = v - cnt;                        // exclusive
        if (lane == 63) { wpres[wid] = __popcll(mask); wcnt[wid] = v; }
        __syncthreads();
        int woffP = 0, totP = 0, woffC = 0, totC = 0;
        #pragma unroll
        for (int w = 0; w < 16; ++w) {
            int p = wpres[w], c = wcnt[w];
            if (w < wid) { woffP += p; woffC += c; }
            totP += p; totC += c;
        }
        if (pres) {
            int c = basePres + woffP + pfx_pres;      // compact slot < MAXU
            cmap[b * Pn + i] = c;
            ccnt[b * MAXU + c] = cnt;
            cursor[b * MAXU + c] = baseCnt + woffC + pfx_cnt;  // ROI-list start
        }
        basePres += totP; baseCnt += totC;
        __syncthreads();
    }
    if (t == 0) { nuniq[b] = basePres; nvalid_arr[b] = baseCnt; }
}

// ---------------- phase 3: scatter ROI ids into per-slot lists ----------------
__global__ void k_fill(const int* __restrict__ roi_label, const int* __restrict__ cmap,
                       int* __restrict__ cursor, int* __restrict__ rlist) {
    int i = blockIdx.x * blockDim.x + threadIdx.x;    // 0..B*R
    int b = i >> 9;
    int lbl = roi_label[i] - 1;
    if (lbl < 0) return;
    int c = cmap[b * Pn + lbl];
    int pos = atomicAdd(&cursor[b * MAXU + c], 1);    // ends at start+cnt
    rlist[b * Rn + pos] = i & 511;                    // local roi id
}

// ---------------- phase 4: gather -> mean -> L2 normalize -> proto (no atomics) -------
__global__ __launch_bounds__(64) void k_proto(
    const float* __restrict__ inputs, const float* __restrict__ cls,
    const int* __restrict__ nuniq, const int* __restrict__ ccnt,
    const int* __restrict__ cursor, const int* __restrict__ rlist,
    float* __restrict__ proto) {
    int slot = blockIdx.x;                            // b*MAXU + c
    int b = slot >> 9;
    int c = slot & (MAXU - 1);
    if (c >= nuniq[b]) return;
    int cnt = ccnt[slot];
    int start = cursor[slot] - cnt;                   // cursor is now end offset
    int t = threadIdx.x;                              // 64 threads x 4 floats
    float4 acc = make_float4(0.f, 0.f, 0.f, 0.f);
    for (int k = 0; k < cnt; ++k) {
        int r = rlist[b * Rn + start + k];
        float cw = cls[b * Rn + r];
        float4 v = *(const float4*)&inputs[(size_t)(b * Rn + r) * Dn + t * 4];
        acc.x += v.x * cw; acc.y += v.y * cw; acc.z += v.z * cw; acc.w += v.w * cw;
    }
    float inv = 1.0f / (float)cnt;
    acc.x *= inv; acc.y *= inv; acc.z *= inv; acc.w *= inv;
    float ss = acc.x*acc.x + acc.y*acc.y + acc.z*acc.z + acc.w*acc.w;
    #pragma unroll
    for (int off = 32; off > 0; off >>= 1) ss += __shfl_xor(ss, off);
    float scale = 1.0f / fmaxf(sqrtf(ss), 1e-12f);
    acc.x *= scale; acc.y *= scale; acc.z *= scale; acc.w *= scale;
    *(float4*)&proto[(size_t)slot * Dn + t * 4] = acc;
}

// ---------------- phase 5: split-bf16 MFMA GEMM + per-chunk logsumexp ----------------
// grid (rt=8, pc=4, b=32) = 1024 blocks, 4 waves/block. ~26.5 KB LDS, VGPR<=128.
#define TRr 64
#define TCc 128
#define KCk 32

__global__ __launch_bounds__(256, 4) void k_loss(
    const float* __restrict__ inputs, const float* __restrict__ cls,
    const int* __restrict__ roi_label, const float* __restrict__ proto,
    const int* __restrict__ cmap, const int* __restrict__ nuniq,
    float* __restrict__ mpart, float* __restrict__ spart,
    float* __restrict__ dlbl_arr)
{
    // XOR-swizzled bf16 tiles: elem off = row*32 + (g ^ ((row>>1)&3))*8, g = k/8
    __shared__ __align__(16) unsigned short xs_hi[TRr * KCk], xs_lo[TRr * KCk];   // 4+4 KB
    __shared__ __align__(16) unsigned short ps_hi[TCc * KCk], ps_lo[TCc * KCk];   // 8+8 KB
    __shared__ float clsv[TRr];
    __shared__ int lblc[TRr];
    __shared__ float mw[4][TRr], sw[4][TRr];          // per-wave partials

    const int t = threadIdx.x;
    const int lane = t & 63, w = t >> 6;
    const int q = lane >> 4, r15 = lane & 15;
    const int b = blockIdx.z;
    const int pc = blockIdx.y;
    const int roiBase = blockIdx.x * TRr;
    const int U = nuniq[b];
    if (pc * TCc >= U) return;                        // uniform block exit

    if (t < TRr) {
        clsv[t] = cls[b * Rn + roiBase + t];
        int lbl = roi_label[b * Rn + roiBase + t] - 1;
        lblc[t] = (lbl >= 0) ? cmap[b * Pn + lbl] : -1;
    }
    __syncthreads();

    floatx4 acc[4][2];
    #pragma unroll
    for (int mt = 0; mt < 4; ++mt)
        #pragma unroll
        for (int nt = 0; nt < 2; ++nt) acc[mt][nt] = (floatx4)0.f;

    for (int kc = 0; kc < Dn / KCk; ++kc) {           // 8 stages
        // ---- stage x: 64 rows x 4 groups of 8; unit per thread ----
        {
            int rr = t >> 2, g = t & 3;
            const float* src = &inputs[(size_t)(b*Rn + roiBase + rr) * Dn + kc*KCk + g*8];
            float4 v0 = *(const float4*)src;
            float4 v1 = *(const float4*)(src + 4);
            float cw = clsv[rr];
            float f[8] = {v0.x*cw, v0.y*cw, v0.z*cw, v0.w*cw,
                          v1.x*cw, v1.y*cw, v1.z*cw, v1.w*cw};
            short8 hi, lo;
            #pragma unroll
            for (int e = 0; e < 8; ++e) {
                unsigned short h = bf16r(f[e]);
                hi[e] = (short)h;
                lo[e] = (short)bf16r(f[e] - bf16tof(h));
            }
            int off = rr * KCk + ((g ^ ((rr >> 1) & 3)) * 8);
            *(short8*)&xs_hi[off] = hi;
            *(short8*)&xs_lo[off] = lo;
        }
        // ---- stage proto: 128 rows x 4 groups; 2 units per thread ----
        #pragma unroll
        for (int s2 = 0; s2 < 2; ++s2) {
            int idx = t + 256 * s2;
            int rr = idx >> 2, g = idx & 3;
            const float* src = &proto[(size_t)(b*MAXU + pc*TCc + rr) * Dn + kc*KCk + g*8];
            float4 v0 = *(const float4*)src;
            float4 v1 = *(const float4*)(src + 4);
            float f[8] = {v0.x, v0.y, v0.z, v0.w, v1.x, v1.y, v1.z, v1.w};
            short8 hi, lo;
            #pragma unroll
            for (int e = 0; e < 8; ++e) {
                unsigned short h = bf16r(f[e]);
                hi[e] = (short)h;
                lo[e] = (short)bf16r(f[e] - bf16tof(h));
            }
            int off = rr * KCk + ((g ^ ((rr >> 1) & 3)) * 8);
            *(short8*)&ps_hi[off] = hi;
            *(short8*)&ps_lo[off] = lo;
        }
        __syncthreads();

        // ---- MFMA: wave w owns protos [w*32, w*32+32) ----
        short8 ah[4], al[4], bh[2], bl[2];
        #pragma unroll
        for (int mt = 0; mt < 4; ++mt) {
            int row = mt * 16 + r15;
            int off = row * KCk + ((q ^ ((row >> 1) & 3)) * 8);
            ah[mt] = *(const short8*)&xs_hi[off];
            al[mt] = *(const short8*)&xs_lo[off];
        }
        #pragma unroll
        for (int nt = 0; nt < 2; ++nt) {
            int row = w * 32 + nt * 16 + r15;
            int off = row * KCk + ((q ^ ((row >> 1) & 3)) * 8);
            bh[nt] = *(const short8*)&ps_hi[off];
            bl[nt] = *(const short8*)&ps_lo[off];
        }
        #pragma unroll
        for (int mt = 0; mt < 4; ++mt)
            #pragma unroll
            for (int nt = 0; nt < 2; ++nt) {
                acc[mt][nt] = __builtin_amdgcn_mfma_f32_16x16x32_bf16(ah[mt], bh[nt], acc[mt][nt], 0, 0, 0);
                acc[mt][nt] = __builtin_amdgcn_mfma_f32_16x16x32_bf16(al[mt], bh[nt], acc[mt][nt], 0, 0, 0);
                acc[mt][nt] = __builtin_amdgcn_mfma_f32_16x16x32_bf16(ah[mt], bl[nt], acc[mt][nt], 0, 0, 0);
            }
        __syncthreads();
    }

    // ---- epilogue: two-pass masked logsumexp per ROI over this wave's 32 protos ----
    // C/D: n = r15, m = q*4 + reg (within 16x16 tile mt)
    const int c0 = pc * TCc + w * 32 + r15;           // nt=0 proto
    const int c1 = c0 + 16;                           // nt=1 proto
    const bool v0 = c0 < U, v1 = c1 < U;
    #pragma unroll
    for (int mt = 0; mt < 4; ++mt)
        #pragma unroll
        for (int reg = 0; reg < 4; ++reg) {
            int mloc = mt * 16 + q * 4 + reg;
            float d0 = acc[mt][0][reg], d1 = acc[mt][1][reg];
            int lc = lblc[mloc];
            if (v0 && c0 == lc) dlbl_arr[b * Rn + roiBase + mloc] = d0;  // unique writer
            if (v1 && c1 == lc) dlbl_arr[b * Rn + roiBase + mloc] = d1;
            float M = fmaxf(v0 ? d0 : NEGBIG, v1 ? d1 : NEGBIG);
            #pragma unroll
            for (int off = 1; off < 16; off <<= 1) M = fmaxf(M, __shfl_xor(M, off));
            float s = (v0 ? __expf(d0 - M) : 0.f) + (v1 ? __expf(d1 - M) : 0.f);
            #pragma unroll
            for (int off = 1; off < 16; off <<= 1) s += __shfl_xor(s, off);
            if (r15 == 0) { mw[w][mloc] = M; sw[w][mloc] = s; }
        }
    __syncthreads();

    if (t < TRr) {
        float M = fmaxf(fmaxf(mw[0][t], mw[1][t]), fmaxf(mw[2][t], mw[3][t]));
        float s = 0.f;
        #pragma unroll
        for (int wv = 0; wv < 4; ++wv) s += sw[wv][t] * __expf(mw[wv][t] - M);
        int roi = b * Rn + roiBase + t;
        mpart[roi * 4 + pc] = M;
        spart[roi * 4 + pc] = s;
    }
}

// ---------------- phase 5b: merge chunk partials -> NLL sum ----------------
__global__ __launch_bounds__(256) void k_merge(
    const int* __restrict__ roi_label, const int* __restrict__ nuniq,
    const float* __restrict__ mpart, const float* __restrict__ spart,
    const float* __restrict__ dlbl_arr, float* __restrict__ nll_sum)
{
    __shared__ float wsum[4];
    int roi = blockIdx.x * 256 + threadIdx.x;
    int b = roi >> 9;
    int lbl = roi_label[roi] - 1;
    float v = 0.f;
    if (lbl >= 0) {
        int U = nuniq[b];
        int nch = (U + TCc - 1) / TCc;
        float m = NEGBIG, s = 0.f;
        for (int pc = 0; pc < nch; ++pc) {
            float om = mpart[roi * 4 + pc], os = spart[roi * 4 + pc];
            float M = fmaxf(m, om);
            s = s * __expf(m - M) + os * __expf(om - M);
            m = M;
        }
        v = m + __logf(s) - dlbl_arr[roi];
    }
    #pragma unroll
    for (int off = 1; off < 64; off <<= 1) v += __shfl_xor(v, off);
    int lane = threadIdx.x & 63, wid = threadIdx.x >> 6;
    if (lane == 0) wsum[wid] = v;
    __syncthreads();
    if (threadIdx.x == 0)
        atomicAdd(nll_sum, wsum[0] + wsum[1] + wsum[2] + wsum[3]);
}

// ---------------- phase 6: finalize ----------------
__global__ void k_final(const float* __restrict__ nll_sum,
                        const int* __restrict__ nvalid_arr, float* __restrict__ out) {
    int s = 0;
    #pragma unroll
    for (int b = 0; b < Bn; ++b) s += nvalid_arr[b];
    out[0] = nll_sum[0] / fmaxf((float)s, 1.0f);
}

extern "C" void kernel_launch(void* const* d_in, const int* in_sizes, int n_in,
                              void* d_out, int out_size, void* d_ws, size_t ws_size,
                              hipStream_t stream) {
    const float* inputs = (const float*)d_in[0];
    const float* cls    = (const float*)d_in[1];
    const int*   roi    = (const int*)d_in[2];
    float* out = (float*)d_out;

    float* wsf = (float*)d_ws;
    int*   wsi = (int*)d_ws;
    int*   counts = wsi + COUNTS_OFF;
    float* nll    = wsf + NLL_OFF;
    float* proto  = wsf + PROTO_OFF;
    int*   cmap   = wsi + CMAP_OFF;
    int*   ccnt   = wsi + CCNT_OFF;
    int*   cursor = wsi + CURS_OFF;
    int*   rlist  = wsi + RLIST_OFF;
    int*   nuniq  = wsi + NUNIQ_OFF;
    int*   nvalid = wsi + NVALID_OFF;
    float* mpart  = wsf + MPART_OFF;
    float* spart  = wsf + SPART_OFF;
    float* dlbl   = wsf + DLBL_OFF;

    hipMemsetAsync(d_ws, 0, (size_t)ZERO_WORDS * 4, stream);
    k_count  <<<(Bn*Rn)/256, 256, 0, stream>>>(roi, counts);
    k_compact<<<Bn, 1024, 0, stream>>>(counts, nuniq, cmap, ccnt, cursor, nvalid);
    k_fill   <<<(Bn*Rn)/256, 256, 0, stream>>>(roi, cmap, cursor, rlist);
    k_proto  <<<Bn*MAXU, 64, 0, stream>>>(inputs, cls, nuniq, ccnt, cursor, rlist, proto);
    dim3 g(Rn / TRr, 4, Bn);
    k_loss   <<<g, 256, 0, stream>>>(inputs, cls, roi, proto, cmap, nuniq, mpart, spart, dlbl);
    k_merge  <<<(Bn*Rn)/256, 256, 0, stream>>>(roi, nuniq, mpart, spart, dlbl, nll);
    k_final  <<<1, 1, 0, stream>>>(nll, nvalid, out);
}

// Round 5
// 119.957 us; speedup vs baseline: 2.8691x; 1.1282x over previous
//
#include <hip/hip_runtime.h>
#include <math.h>

#define Bn 32
#define Rn 512
#define Dn 256
#define Pn 5532
#define MAXU 512
#define NEGBIG -3.0e38f

typedef short short8 __attribute__((ext_vector_type(8)));
typedef short short4v __attribute__((ext_vector_type(4)));
typedef float floatx4 __attribute__((ext_vector_type(4)));

// ---- workspace layout (4-byte words). Only [0, ZERO_WORDS) is memset. ----
#define COUNTS_OFF   0
#define NLL_OFF      (Bn*Pn)                        // 177024
#define ZERO_WORDS   (NLL_OFF + 4)                  // pad to 16B multiple (177028)
#define XBF_OFF      ZERO_WORDS                     // bf16 scaled inputs, B*R*D ushorts
#define XBF_WORDS    (Bn*Rn*Dn/2)                   // 2,097,152
#define PBF_OFF      (XBF_OFF + XBF_WORDS)          // bf16 prototypes, B*MAXU*D ushorts
#define PBF_WORDS    (Bn*MAXU*Dn/2)
#define CMAP_OFF     (PBF_OFF + PBF_WORDS)
#define CCNT_OFF     (CMAP_OFF + Bn*Pn)
#define CURS_OFF     (CCNT_OFF + Bn*MAXU)
#define RLIST_OFF    (CURS_OFF + Bn*MAXU)
#define NUNIQ_OFF    (RLIST_OFF + Bn*Rn)
#define NVALID_OFF   (NUNIQ_OFF + 32)
#define MPART_OFF    (NVALID_OFF + 32)
#define SPART_OFF    (MPART_OFF + Bn*Rn*4)
#define DLBL_OFF     (SPART_OFF + Bn*Rn*4)
// end = DLBL_OFF + Bn*Rn ~= 4.75M words ~= 19.0 MB

__device__ __forceinline__ unsigned short bf16r(float f) {   // fp32 -> bf16 RNE
    union { float f; unsigned int u; } c; c.f = f;
    return (unsigned short)((c.u + 0x7FFFu + ((c.u >> 16) & 1u)) >> 16);
}

// async global->LDS, 16B per lane. LDS dest = wave-uniform base + lane*16.
__device__ __forceinline__ void async16(void* lds, const void* g) {
    auto* l3 = reinterpret_cast<__attribute__((address_space(3))) unsigned int*>(
                   reinterpret_cast<size_t>(lds));
    auto* g1 = reinterpret_cast<const __attribute__((address_space(1))) unsigned int*>(
                   reinterpret_cast<size_t>(g));
    __builtin_amdgcn_global_load_lds(g1, l3, 16, 0, 0);
}

// ---------------- phase 0: convert inputs*cls -> bf16 once ----------------
__global__ __launch_bounds__(256) void k_prep(const float* __restrict__ inputs,
                                              const float* __restrict__ cls,
                                              unsigned short* __restrict__ xbf) {
    int i8 = blockIdx.x * 256 + threadIdx.x;          // 8 elems per thread
    int e = i8 * 8;
    int row = e >> 8;                                 // /Dn
    float cw = cls[row];
    float4 v0 = *(const float4*)&inputs[e];
    float4 v1 = *(const float4*)&inputs[e + 4];
    short8 o;
    o[0] = (short)bf16r(v0.x * cw); o[1] = (short)bf16r(v0.y * cw);
    o[2] = (short)bf16r(v0.z * cw); o[3] = (short)bf16r(v0.w * cw);
    o[4] = (short)bf16r(v1.x * cw); o[5] = (short)bf16r(v1.y * cw);
    o[6] = (short)bf16r(v1.z * cw); o[7] = (short)bf16r(v1.w * cw);
    *(short8*)&xbf[e] = o;
}

// ---------------- phase 1: count labels per image ----------------
__global__ void k_count(const int* __restrict__ roi_label,
                        int* __restrict__ counts) {
    int i = blockIdx.x * blockDim.x + threadIdx.x;
    if (i >= Bn * Rn) return;
    int b = i >> 9;
    int lbl = roi_label[i] - 1;
    if (lbl >= 0) atomicAdd(&counts[b * Pn + lbl], 1);
}

// ---------------- phase 2: compact slots + CSR offsets via block scans ----------------
__global__ __launch_bounds__(1024) void k_compact(
    const int* __restrict__ counts, int* __restrict__ nuniq,
    int* __restrict__ cmap, int* __restrict__ ccnt,
    int* __restrict__ cursor, int* __restrict__ nvalid_arr) {
    const int b = blockIdx.x;
    const int t = threadIdx.x;
    const int lane = t & 63, wid = t >> 6;            // 16 waves
    __shared__ int wpres[16], wcnt[16];
    int basePres = 0, baseCnt = 0;                    // replicated
    for (int i0 = 0; i0 < Pn; i0 += 1024) {
        int i = i0 + t;
        int cnt = (i < Pn) ? counts[b * Pn + i] : 0;
        bool pres = cnt > 0;
        unsigned long long mask = __ballot(pres);
        int pfx_pres = __popcll(mask & ((1ULL << lane) - 1ULL));
        int v = cnt;
        #pragma unroll
        for (int off = 1; off < 64; off <<= 1) {
            int u = __shfl_up(v, off);
            if (lane >= off) v += u;
        }
        int pfx_cnt = v - cnt;                        // exclusive
        if (lane == 63) { wpres[wid] = __popcll(mask); wcnt[wid] = v; }
        __syncthreads();
        int woffP = 0, totP = 0, woffC = 0, totC = 0;
        #pragma unroll
        for (int w = 0; w < 16; ++w) {
            int p = wpres[w], c = wcnt[w];
            if (w < wid) { woffP += p; woffC += c; }
            totP += p; totC += c;
        }
        if (pres) {
            int c = basePres + woffP + pfx_pres;      // compact slot < MAXU
            cmap[b * Pn + i] = c;
            ccnt[b * MAXU + c] = cnt;
            cursor[b * MAXU + c] = baseCnt + woffC + pfx_cnt;
        }
        basePres += totP; baseCnt += totC;
        __syncthreads();
    }
    if (t == 0) { nuniq[b] = basePres; nvalid_arr[b] = baseCnt; }
}

// ---------------- phase 3: scatter ROI ids into per-slot lists ----------------
__global__ void k_fill(const int* __restrict__ roi_label, const int* __restrict__ cmap,
                       int* __restrict__ cursor, int* __restrict__ rlist) {
    int i = blockIdx.x * blockDim.x + threadIdx.x;
    int b = i >> 9;
    int lbl = roi_label[i] - 1;
    if (lbl < 0) return;
    int c = cmap[b * Pn + lbl];
    int pos = atomicAdd(&cursor[b * MAXU + c], 1);
    rlist[b * Rn + pos] = i & 511;
}

// ---------- phase 4: gather -> mean -> L2 normalize -> bf16 proto (no atomics) -------
__global__ __launch_bounds__(64) void k_proto(
    const float* __restrict__ inputs, const float* __restrict__ cls,
    const int* __restrict__ nuniq, const int* __restrict__ ccnt,
    const int* __restrict__ cursor, const int* __restrict__ rlist,
    unsigned short* __restrict__ pbf) {
    int slot = blockIdx.x;                            // b*MAXU + c
    int b = slot >> 9;
    int c = slot & (MAXU - 1);
    if (c >= nuniq[b]) return;
    int cnt = ccnt[slot];
    int start = cursor[slot] - cnt;                   // cursor is end offset after k_fill
    int t = threadIdx.x;                              // 64 threads x 4 floats
    float4 acc = make_float4(0.f, 0.f, 0.f, 0.f);
    for (int k = 0; k < cnt; ++k) {
        int r = rlist[b * Rn + start + k];
        float cw = cls[b * Rn + r];
        float4 v = *(const float4*)&inputs[(size_t)(b * Rn + r) * Dn + t * 4];
        acc.x += v.x * cw; acc.y += v.y * cw; acc.z += v.z * cw; acc.w += v.w * cw;
    }
    float inv = 1.0f / (float)cnt;
    acc.x *= inv; acc.y *= inv; acc.z *= inv; acc.w *= inv;
    float ss = acc.x*acc.x + acc.y*acc.y + acc.z*acc.z + acc.w*acc.w;
    #pragma unroll
    for (int off = 32; off > 0; off >>= 1) ss += __shfl_xor(ss, off);
    float scale = 1.0f / fmaxf(sqrtf(ss), 1e-12f);
    short4v o;
    o[0] = (short)bf16r(acc.x * scale); o[1] = (short)bf16r(acc.y * scale);
    o[2] = (short)bf16r(acc.z * scale); o[3] = (short)bf16r(acc.w * scale);
    *(short4v*)&pbf[(size_t)slot * Dn + t * 4] = o;
}

// -------- phase 5: bf16 MFMA GEMM via async double-buffered LDS + logsumexp --------
// grid (rt=8, pc=4, b=32) = 1024 blocks, 4 waves/block, ~26 KB LDS -> 4 blocks/CU.
#define TRr 64
#define TCc 128
#define KCk 32

__global__ __launch_bounds__(256, 4) void k_loss(
    const unsigned short* __restrict__ xbf, const unsigned short* __restrict__ pbf,
    const int* __restrict__ roi_label, const int* __restrict__ cmap,
    const int* __restrict__ nuniq,
    float* __restrict__ mpart, float* __restrict__ spart,
    float* __restrict__ dlbl_arr)
{
    // XOR-swizzled bf16 tiles (content group g stored at gpos = g ^ ((row>>1)&3)),
    // realized via the per-lane GLOBAL address so the LDS side stays lane*16-linear.
    __shared__ __align__(16) unsigned short xs[2][TRr * KCk];   // 2 x 4 KB
    __shared__ __align__(16) unsigned short ps[2][TCc * KCk];   // 2 x 8 KB
    __shared__ int lblc[TRr];
    __shared__ float mw[4][TRr], sw[4][TRr];

    const int t = threadIdx.x;
    const int lane = t & 63, w = t >> 6;
    const int q = lane >> 4, r15 = lane & 15;
    const int b = blockIdx.z;
    const int pc = blockIdx.y;
    const int roiBase = blockIdx.x * TRr;
    const int U = nuniq[b];
    if (pc * TCc >= U) return;                        // uniform block exit

    if (t < TRr) {
        int lbl = roi_label[b * Rn + roiBase + t] - 1;
        lblc[t] = (lbl >= 0) ? cmap[b * Pn + lbl] : -1;
    }

    // wave w stages chunks {w, w+4, w+8} of 12: chunks 0..3 = x, 4..11 = proto
    const int s0 = w * 64 + lane;                     // x-chunk slot for this lane
    const int xrow = s0 >> 2;
    const int xg = (s0 & 3) ^ ((xrow >> 1) & 3);
    const size_t xgbase = (size_t)(b * Rn + roiBase + xrow) * Dn + xg * 8;
    int prow[2], pg[2];
    #pragma unroll
    for (int cc = 0; cc < 2; ++cc) {
        int s = (w + cc * 4) * 64 + lane;             // proto chunks w, w+4 (of 8)
        prow[cc] = s >> 2;
        pg[cc] = (s & 3) ^ ((prow[cc] >> 1) & 3);
    }

    #define ISSUE(kc, buf)                                                        \
        do {                                                                      \
            async16(&xs[buf][w * 512], xbf + xgbase + (kc) * KCk);                \
            async16(&ps[buf][w * 512],                                            \
                    pbf + (size_t)(b * MAXU + pc * TCc + prow[0]) * Dn            \
                        + (kc) * KCk + pg[0] * 8);                                \
            async16(&ps[buf][(w + 4) * 512],                                      \
                    pbf + (size_t)(b * MAXU + pc * TCc + prow[1]) * Dn            \
                        + (kc) * KCk + pg[1] * 8);                                \
        } while (0)

    ISSUE(0, 0);

    floatx4 acc[4][2];
    #pragma unroll
    for (int mt = 0; mt < 4; ++mt)
        #pragma unroll
        for (int nt = 0; nt < 2; ++nt) acc[mt][nt] = (floatx4)0.f;

    for (int kc = 0; kc < Dn / KCk; ++kc) {           // 8 stages
        const int cur = kc & 1;
        __syncthreads();                              // buf[cur] loads complete here
        if (kc < Dn / KCk - 1) ISSUE(kc + 1, cur ^ 1);// in flight during MFMA below

        short8 a[4], bb[2];
        #pragma unroll
        for (int mt = 0; mt < 4; ++mt) {
            int row = mt * 16 + r15;
            int off = row * KCk + ((q ^ ((row >> 1) & 3)) * 8);
            a[mt] = *(const short8*)&xs[cur][off];
        }
        #pragma unroll
        for (int nt = 0; nt < 2; ++nt) {
            int row = w * 32 + nt * 16 + r15;
            int off = row * KCk + ((q ^ ((row >> 1) & 3)) * 8);
            bb[nt] = *(const short8*)&ps[cur][off];
        }
        #pragma unroll
        for (int mt = 0; mt < 4; ++mt)
            #pragma unroll
            for (int nt = 0; nt < 2; ++nt)
                acc[mt][nt] = __builtin_amdgcn_mfma_f32_16x16x32_bf16(a[mt], bb[nt], acc[mt][nt], 0, 0, 0);
    }

    // ---- epilogue: masked logsumexp per ROI over this wave's 32 protos ----
    // C/D layout: n = r15, m = q*4 + reg (within 16x16 tile mt)
    const int c0 = pc * TCc + w * 32 + r15;
    const int c1 = c0 + 16;
    const bool v0 = c0 < U, v1 = c1 < U;
    #pragma unroll
    for (int mt = 0; mt < 4; ++mt)
        #pragma unroll
        for (int reg = 0; reg < 4; ++reg) {
            int mloc = mt * 16 + q * 4 + reg;
            float d0 = acc[mt][0][reg], d1 = acc[mt][1][reg];
            int lc = lblc[mloc];
            if (v0 && c0 == lc) dlbl_arr[b * Rn + roiBase + mloc] = d0;  // unique writer
            if (v1 && c1 == lc) dlbl_arr[b * Rn + roiBase + mloc] = d1;
            float M = fmaxf(v0 ? d0 : NEGBIG, v1 ? d1 : NEGBIG);
            #pragma unroll
            for (int off = 1; off < 16; off <<= 1) M = fmaxf(M, __shfl_xor(M, off));
            float s = (v0 ? __expf(d0 - M) : 0.f) + (v1 ? __expf(d1 - M) : 0.f);
            #pragma unroll
            for (int off = 1; off < 16; off <<= 1) s += __shfl_xor(s, off);
            if (r15 == 0) { mw[w][mloc] = M; sw[w][mloc] = s; }
        }
    __syncthreads();

    if (t < TRr) {
        float M = fmaxf(fmaxf(mw[0][t], mw[1][t]), fmaxf(mw[2][t], mw[3][t]));
        float s = 0.f;
        #pragma unroll
        for (int wv = 0; wv < 4; ++wv) s += sw[wv][t] * __expf(mw[wv][t] - M);
        int roi = b * Rn + roiBase + t;
        mpart[roi * 4 + pc] = M;
        spart[roi * 4 + pc] = s;
    }
    #undef ISSUE
}

// ---------------- phase 5b: merge chunk partials -> NLL sum ----------------
__global__ __launch_bounds__(256) void k_merge(
    const int* __restrict__ roi_label, const int* __restrict__ nuniq,
    const float* __restrict__ mpart, const float* __restrict__ spart,
    const float* __restrict__ dlbl_arr, float* __restrict__ nll_sum)
{
    __shared__ float wsum[4];
    int roi = blockIdx.x * 256 + threadIdx.x;
    int b = roi >> 9;
    int lbl = roi_label[roi] - 1;
    float v = 0.f;
    if (lbl >= 0) {
        int U = nuniq[b];
        int nch = (U + TCc - 1) / TCc;
        float m = NEGBIG, s = 0.f;
        for (int pc = 0; pc < nch; ++pc) {
            float om = mpart[roi * 4 + pc], os = spart[roi * 4 + pc];
            float M = fmaxf(m, om);
            s = s * __expf(m - M) + os * __expf(om - M);
            m = M;
        }
        v = m + __logf(s) - dlbl_arr[roi];
    }
    #pragma unroll
    for (int off = 1; off < 64; off <<= 1) v += __shfl_xor(v, off);
    int lane = threadIdx.x & 63, wid = threadIdx.x >> 6;
    if (lane == 0) wsum[wid] = v;
    __syncthreads();
    if (threadIdx.x == 0)
        atomicAdd(nll_sum, wsum[0] + wsum[1] + wsum[2] + wsum[3]);
}

// ---------------- phase 6: finalize ----------------
__global__ void k_final(const float* __restrict__ nll_sum,
                        const int* __restrict__ nvalid_arr, float* __restrict__ out) {
    int s = 0;
    #pragma unroll
    for (int b = 0; b < Bn; ++b) s += nvalid_arr[b];
    out[0] = nll_sum[0] / fmaxf((float)s, 1.0f);
}

extern "C" void kernel_launch(void* const* d_in, const int* in_sizes, int n_in,
                              void* d_out, int out_size, void* d_ws, size_t ws_size,
                              hipStream_t stream) {
    const float* inputs = (const float*)d_in[0];
    const float* cls    = (const float*)d_in[1];
    const int*   roi    = (const int*)d_in[2];
    float* out = (float*)d_out;

    float* wsf = (float*)d_ws;
    int*   wsi = (int*)d_ws;
    int*   counts = wsi + COUNTS_OFF;
    float* nll    = wsf + NLL_OFF;
    unsigned short* xbf = (unsigned short*)(wsi + XBF_OFF);
    unsigned short* pbf = (unsigned short*)(wsi + PBF_OFF);
    int*   cmap   = wsi + CMAP_OFF;
    int*   ccnt   = wsi + CCNT_OFF;
    int*   cursor = wsi + CURS_OFF;
    int*   rlist  = wsi + RLIST_OFF;
    int*   nuniq  = wsi + NUNIQ_OFF;
    int*   nvalid = wsi + NVALID_OFF;
    float* mpart  = wsf + MPART_OFF;
    float* spart  = wsf + SPART_OFF;
    float* dlbl   = wsf + DLBL_OFF;

    hipMemsetAsync(d_ws, 0, (size_t)ZERO_WORDS * 4, stream);
    k_count  <<<(Bn*Rn)/256, 256, 0, stream>>>(roi, counts);
    k_prep   <<<(Bn*Rn*Dn)/(256*8), 256, 0, stream>>>(inputs, cls, xbf);
    k_compact<<<Bn, 1024, 0, stream>>>(counts, nuniq, cmap, ccnt, cursor, nvalid);
    k_fill   <<<(Bn*Rn)/256, 256, 0, stream>>>(roi, cmap, cursor, rlist);
    k_proto  <<<Bn*MAXU, 64, 0, stream>>>(inputs, cls, nuniq, ccnt, cursor, rlist, pbf);
    dim3 g(Rn / TRr, 4, Bn);
    k_loss   <<<g, 256, 0, stream>>>(xbf, pbf, roi, cmap, nuniq, mpart, spart, dlbl);
    k_merge  <<<(Bn*Rn)/256, 256, 0, stream>>>(roi, nuniq, mpart, spart, dlbl, nll);
    k_final  <<<1, 1, 0, stream>>>(nll, nvalid, out);
}

// Round 6
// 115.579 us; speedup vs baseline: 2.9778x; 1.0379x over previous
//
#include <hip/hip_runtime.h>
#include <math.h>

#define Bn 32
#define Rn 512
#define Dn 256
#define Pn 5532
#define MAXU 512
#define NEGBIG -3.0e38f

typedef short short8 __attribute__((ext_vector_type(8)));
typedef short short4v __attribute__((ext_vector_type(4)));
typedef float floatx4 __attribute__((ext_vector_type(4)));

// ---- workspace layout (4-byte words). Only [0, ZERO_WORDS) is memset. ----
#define COUNTS_OFF   0
#define NLL_OFF      (Bn*Pn)                        // 177024
#define TICKET_OFF   (NLL_OFF + 1)
#define ZERO_WORDS   (TICKET_OFF + 3)               // pad to 16B multiple
#define XBF_OFF      ZERO_WORDS                     // bf16 scaled inputs
#define XBF_WORDS    (Bn*Rn*Dn/2)
#define PBF_OFF      (XBF_OFF + XBF_WORDS)          // bf16 prototypes
#define PBF_WORDS    (Bn*MAXU*Dn/2)
#define CMAP_OFF     (PBF_OFF + PBF_WORDS)
#define CCNT_OFF     (CMAP_OFF + Bn*Pn)
#define CURS_OFF     (CCNT_OFF + Bn*MAXU)
#define RLIST_OFF    (CURS_OFF + Bn*MAXU)
#define NUNIQ_OFF    (RLIST_OFF + Bn*Rn)
#define NVALID_OFF   (NUNIQ_OFF + 32)
#define MPART_OFF    (NVALID_OFF + 32)
#define SPART_OFF    (MPART_OFF + Bn*Rn*4)
#define DLBL_OFF     (SPART_OFF + Bn*Rn*4)
// end ~= 4.75M words ~= 19.0 MB

__device__ __forceinline__ unsigned short bf16r(float f) {   // fp32 -> bf16 RNE
    union { float f; unsigned int u; } c; c.f = f;
    return (unsigned short)((c.u + 0x7FFFu + ((c.u >> 16) & 1u)) >> 16);
}

// async global->LDS, 16B per lane. LDS dest = wave-uniform base + lane*16.
__device__ __forceinline__ void async16(void* lds, const void* g) {
    auto* l3 = reinterpret_cast<__attribute__((address_space(3))) unsigned int*>(
                   reinterpret_cast<size_t>(lds));
    auto* g1 = reinterpret_cast<const __attribute__((address_space(1))) unsigned int*>(
                   reinterpret_cast<size_t>(g));
    __builtin_amdgcn_global_load_lds(g1, l3, 16, 0, 0);
}

// ------- phase 0+1 fused: convert inputs*cls -> bf16; blocks 0..63 also count -------
__global__ __launch_bounds__(256) void k_prep(const float* __restrict__ inputs,
                                              const float* __restrict__ cls,
                                              const int* __restrict__ roi_label,
                                              unsigned short* __restrict__ xbf,
                                              int* __restrict__ counts) {
    int i8 = blockIdx.x * 256 + threadIdx.x;
    if (i8 < Bn * Rn) {                               // count duty (blocks 0..63)
        int b = i8 >> 9;
        int lbl = roi_label[i8] - 1;
        if (lbl >= 0) atomicAdd(&counts[b * Pn + lbl], 1);
    }
    int e = i8 * 8;
    int row = e >> 8;
    float cw = cls[row];
    float4 v0 = *(const float4*)&inputs[e];
    float4 v1 = *(const float4*)&inputs[e + 4];
    short8 o;
    o[0] = (short)bf16r(v0.x * cw); o[1] = (short)bf16r(v0.y * cw);
    o[2] = (short)bf16r(v0.z * cw); o[3] = (short)bf16r(v0.w * cw);
    o[4] = (short)bf16r(v1.x * cw); o[5] = (short)bf16r(v1.y * cw);
    o[6] = (short)bf16r(v1.z * cw); o[7] = (short)bf16r(v1.w * cw);
    *(short8*)&xbf[e] = o;
}

// -------- phase 2+3 fused: compact slots (scan) + CSR scatter, all in-block --------
__global__ __launch_bounds__(1024) void k_compact(
    const int* __restrict__ roi_label, const int* __restrict__ counts,
    int* __restrict__ nuniq, int* __restrict__ cmap, int* __restrict__ ccnt,
    int* __restrict__ cursor, int* __restrict__ rlist, int* __restrict__ nvalid_arr) {
    const int b = blockIdx.x;
    const int t = threadIdx.x;
    const int lane = t & 63, wid = t >> 6;            // 16 waves
    __shared__ int wpres[16], wcnt[16];
    __shared__ int cmap_lds[Pn];                      // 21.6 KB
    __shared__ int curs_lds[MAXU];
    int basePres = 0, baseCnt = 0;                    // replicated
    for (int i0 = 0; i0 < Pn; i0 += 1024) {
        int i = i0 + t;
        int cnt = (i < Pn) ? counts[b * Pn + i] : 0;
        bool pres = cnt > 0;
        unsigned long long mask = __ballot(pres);
        int pfx_pres = __popcll(mask & ((1ULL << lane) - 1ULL));
        int v = cnt;
        #pragma unroll
        for (int off = 1; off < 64; off <<= 1) {
            int u = __shfl_up(v, off);
            if (lane >= off) v += u;
        }
        int pfx_cnt = v - cnt;                        // exclusive
        if (lane == 63) { wpres[wid] = __popcll(mask); wcnt[wid] = v; }
        __syncthreads();
        int woffP = 0, totP = 0, woffC = 0, totC = 0;
        #pragma unroll
        for (int w = 0; w < 16; ++w) {
            int p = wpres[w], c = wcnt[w];
            if (w < wid) { woffP += p; woffC += c; }
            totP += p; totC += c;
        }
        if (pres) {
            int c = basePres + woffP + pfx_pres;      // compact slot < MAXU
            cmap_lds[i] = c;
            cmap[b * Pn + i] = c;                     // k_loss needs it
            ccnt[b * MAXU + c] = cnt;
            curs_lds[c] = baseCnt + woffC + pfx_cnt;  // start offset
        }
        basePres += totP; baseCnt += totC;
        __syncthreads();
    }
    // scatter this image's 512 ROIs via LDS atomics
    if (t < Rn) {
        int lbl = roi_label[b * Rn + t] - 1;
        if (lbl >= 0) {
            int c = cmap_lds[lbl];
            int pos = atomicAdd(&curs_lds[c], 1);
            rlist[b * Rn + pos] = t;
        }
    }
    __syncthreads();
    if (t < MAXU && t < basePres)
        cursor[b * MAXU + t] = curs_lds[t];           // end offset (= start + cnt)
    if (t == 0) { nuniq[b] = basePres; nvalid_arr[b] = baseCnt; }
}

// ---------- phase 4: gather -> mean -> L2 normalize -> bf16 proto ----------
__global__ __launch_bounds__(64) void k_proto(
    const float* __restrict__ inputs, const float* __restrict__ cls,
    const int* __restrict__ nuniq, const int* __restrict__ ccnt,
    const int* __restrict__ cursor, const int* __restrict__ rlist,
    unsigned short* __restrict__ pbf) {
    int slot = blockIdx.x;                            // b*MAXU + c
    int b = slot >> 9;
    int c = slot & (MAXU - 1);
    if (c >= nuniq[b]) return;
    int cnt = ccnt[slot];
    int start = cursor[slot] - cnt;
    int t = threadIdx.x;
    float4 acc = make_float4(0.f, 0.f, 0.f, 0.f);
    for (int k = 0; k < cnt; ++k) {
        int r = rlist[b * Rn + start + k];
        float cw = cls[b * Rn + r];
        float4 v = *(const float4*)&inputs[(size_t)(b * Rn + r) * Dn + t * 4];
        acc.x += v.x * cw; acc.y += v.y * cw; acc.z += v.z * cw; acc.w += v.w * cw;
    }
    float inv = 1.0f / (float)cnt;
    acc.x *= inv; acc.y *= inv; acc.z *= inv; acc.w *= inv;
    float ss = acc.x*acc.x + acc.y*acc.y + acc.z*acc.z + acc.w*acc.w;
    #pragma unroll
    for (int off = 32; off > 0; off >>= 1) ss += __shfl_xor(ss, off);
    float scale = 1.0f / fmaxf(sqrtf(ss), 1e-12f);
    short4v o;
    o[0] = (short)bf16r(acc.x * scale); o[1] = (short)bf16r(acc.y * scale);
    o[2] = (short)bf16r(acc.z * scale); o[3] = (short)bf16r(acc.w * scale);
    *(short4v*)&pbf[(size_t)slot * Dn + t * 4] = o;
}

// -------- phase 5: bf16 MFMA GEMM, 128x128 tiles, async dbuf LDS + logsumexp --------
// grid (rt=4, pc=4, b=32) = 512 blocks, 4 waves/block, ~37 KB LDS -> 2+/CU.
#define TRr 128
#define TCc 128
#define KCk 32

__global__ __launch_bounds__(256, 3) void k_loss(
    const unsigned short* __restrict__ xbf, const unsigned short* __restrict__ pbf,
    const int* __restrict__ roi_label, const int* __restrict__ cmap,
    const int* __restrict__ nuniq,
    float* __restrict__ mpart, float* __restrict__ spart,
    float* __restrict__ dlbl_arr)
{
    // XOR-swizzled bf16 tiles (content group g at gpos = g ^ ((row>>1)&3)),
    // realized via per-lane GLOBAL address; LDS side stays lane*16-linear.
    __shared__ __align__(16) unsigned short xs[2][TRr * KCk];   // 2 x 8 KB
    __shared__ __align__(16) unsigned short ps[2][TCc * KCk];   // 2 x 8 KB
    __shared__ int lblc[TRr];
    __shared__ float mw[4][TRr], sw[4][TRr];

    const int t = threadIdx.x;
    const int lane = t & 63, w = t >> 6;
    const int q = lane >> 4, r15 = lane & 15;
    const int b = blockIdx.z;
    const int pc = blockIdx.y;
    const int roiBase = blockIdx.x * TRr;
    const int U = nuniq[b];
    if (pc * TCc >= U) return;                        // uniform block exit

    if (t < TRr) {
        int lbl = roi_label[b * Rn + roiBase + t] - 1;
        lblc[t] = (lbl >= 0) ? cmap[b * Pn + lbl] : -1;
    }

    // 16 chunks/stage (8 xs + 8 ps); wave w stages xs {w, w+4}, ps {w, w+4}.
    int xrow[2], xg[2], prow[2], pg[2];
    #pragma unroll
    for (int cc = 0; cc < 2; ++cc) {
        int s = (w + cc * 4) * 64 + lane;
        xrow[cc] = s >> 2; xg[cc] = (s & 3) ^ ((xrow[cc] >> 1) & 3);
        prow[cc] = s >> 2; pg[cc] = xg[cc];
    }

    #define ISSUE(kc, buf)                                                         \
        do {                                                                       \
            async16(&xs[buf][w * 512],                                             \
                    xbf + (size_t)(b * Rn + roiBase + xrow[0]) * Dn                \
                        + (kc) * KCk + xg[0] * 8);                                 \
            async16(&xs[buf][(w + 4) * 512],                                       \
                    xbf + (size_t)(b * Rn + roiBase + xrow[1]) * Dn                \
                        + (kc) * KCk + xg[1] * 8);                                 \
            async16(&ps[buf][w * 512],                                             \
                    pbf + (size_t)(b * MAXU + pc * TCc + prow[0]) * Dn             \
                        + (kc) * KCk + pg[0] * 8);                                 \
            async16(&ps[buf][(w + 4) * 512],                                       \
                    pbf + (size_t)(b * MAXU + pc * TCc + prow[1]) * Dn             \
                        + (kc) * KCk + pg[1] * 8);                                 \
        } while (0)

    ISSUE(0, 0);

    floatx4 acc[8][2];
    #pragma unroll
    for (int mt = 0; mt < 8; ++mt)
        #pragma unroll
        for (int nt = 0; nt < 2; ++nt) acc[mt][nt] = (floatx4)0.f;

    for (int kc = 0; kc < Dn / KCk; ++kc) {           // 8 stages
        const int cur = kc & 1;
        __syncthreads();                              // buf[cur] resident
        if (kc < Dn / KCk - 1) ISSUE(kc + 1, cur ^ 1);

        short8 bb[2];
        #pragma unroll
        for (int nt = 0; nt < 2; ++nt) {
            int row = w * 32 + nt * 16 + r15;
            int off = row * KCk + ((q ^ ((row >> 1) & 3)) * 8);
            bb[nt] = *(const short8*)&ps[cur][off];
        }
        #pragma unroll
        for (int mt = 0; mt < 8; ++mt) {
            int row = mt * 16 + r15;
            int off = row * KCk + ((q ^ ((row >> 1) & 3)) * 8);
            short8 a = *(const short8*)&xs[cur][off];
            acc[mt][0] = __builtin_amdgcn_mfma_f32_16x16x32_bf16(a, bb[0], acc[mt][0], 0, 0, 0);
            acc[mt][1] = __builtin_amdgcn_mfma_f32_16x16x32_bf16(a, bb[1], acc[mt][1], 0, 0, 0);
        }
    }

    // ---- epilogue: masked logsumexp per ROI over this wave's 32 protos ----
    // C/D layout: n = r15, m = q*4 + reg (within 16x16 tile mt)
    const int c0 = pc * TCc + w * 32 + r15;
    const int c1 = c0 + 16;
    const bool v0 = c0 < U, v1 = c1 < U;
    #pragma unroll
    for (int mt = 0; mt < 8; ++mt)
        #pragma unroll
        for (int reg = 0; reg < 4; ++reg) {
            int mloc = mt * 16 + q * 4 + reg;
            float d0 = acc[mt][0][reg], d1 = acc[mt][1][reg];
            int lc = lblc[mloc];
            if (v0 && c0 == lc) dlbl_arr[b * Rn + roiBase + mloc] = d0;  // unique writer
            if (v1 && c1 == lc) dlbl_arr[b * Rn + roiBase + mloc] = d1;
            float M = fmaxf(v0 ? d0 : NEGBIG, v1 ? d1 : NEGBIG);
            #pragma unroll
            for (int off = 1; off < 16; off <<= 1) M = fmaxf(M, __shfl_xor(M, off));
            float s = (v0 ? __expf(d0 - M) : 0.f) + (v1 ? __expf(d1 - M) : 0.f);
            #pragma unroll
            for (int off = 1; off < 16; off <<= 1) s += __shfl_xor(s, off);
            if (r15 == 0) { mw[w][mloc] = M; sw[w][mloc] = s; }
        }
    __syncthreads();

    if (t < TRr) {
        float M = fmaxf(fmaxf(mw[0][t], mw[1][t]), fmaxf(mw[2][t], mw[3][t]));
        float s = 0.f;
        #pragma unroll
        for (int wv = 0; wv < 4; ++wv) s += sw[wv][t] * __expf(mw[wv][t] - M);
        int roi = b * Rn + roiBase + t;
        mpart[roi * 4 + pc] = M;
        spart[roi * 4 + pc] = s;
    }
    #undef ISSUE
}

// -------- phase 5b+6 fused: merge partials -> NLL sum; last block finalizes --------
__global__ __launch_bounds__(256) void k_merge(
    const int* __restrict__ roi_label, const int* __restrict__ nuniq,
    const float* __restrict__ mpart, const float* __restrict__ spart,
    const float* __restrict__ dlbl_arr, float* __restrict__ nll_sum,
    int* __restrict__ ticket, const int* __restrict__ nvalid_arr,
    float* __restrict__ out)
{
    __shared__ float wsum[4];
    int roi = blockIdx.x * 256 + threadIdx.x;
    int b = roi >> 9;
    int lbl = roi_label[roi] - 1;
    float v = 0.f;
    if (lbl >= 0) {
        int U = nuniq[b];
        int nch = (U + TCc - 1) / TCc;
        float m = NEGBIG, s = 0.f;
        for (int pc = 0; pc < nch; ++pc) {
            float om = mpart[roi * 4 + pc], os = spart[roi * 4 + pc];
            float M = fmaxf(m, om);
            s = s * __expf(m - M) + os * __expf(om - M);
            m = M;
        }
        v = m + __logf(s) - dlbl_arr[roi];
    }
    #pragma unroll
    for (int off = 1; off < 64; off <<= 1) v += __shfl_xor(v, off);
    int lane = threadIdx.x & 63, wid = threadIdx.x >> 6;
    if (lane == 0) wsum[wid] = v;
    __syncthreads();
    if (threadIdx.x == 0) {
        atomicAdd(nll_sum, wsum[0] + wsum[1] + wsum[2] + wsum[3]);
        __threadfence();
        int tk = atomicAdd(ticket, 1);
        if (tk == gridDim.x - 1) {                    // last block finalizes
            __threadfence();
            int s = 0;
            #pragma unroll
            for (int bb = 0; bb < Bn; ++bb) s += nvalid_arr[bb];
            out[0] = nll_sum[0] / fmaxf((float)s, 1.0f);
        }
    }
}

extern "C" void kernel_launch(void* const* d_in, const int* in_sizes, int n_in,
                              void* d_out, int out_size, void* d_ws, size_t ws_size,
                              hipStream_t stream) {
    const float* inputs = (const float*)d_in[0];
    const float* cls    = (const float*)d_in[1];
    const int*   roi    = (const int*)d_in[2];
    float* out = (float*)d_out;

    float* wsf = (float*)d_ws;
    int*   wsi = (int*)d_ws;
    int*   counts = wsi + COUNTS_OFF;
    float* nll    = wsf + NLL_OFF;
    int*   ticket = wsi + TICKET_OFF;
    unsigned short* xbf = (unsigned short*)(wsi + XBF_OFF);
    unsigned short* pbf = (unsigned short*)(wsi + PBF_OFF);
    int*   cmap   = wsi + CMAP_OFF;
    int*   ccnt   = wsi + CCNT_OFF;
    int*   cursor = wsi + CURS_OFF;
    int*   rlist  = wsi + RLIST_OFF;
    int*   nuniq  = wsi + NUNIQ_OFF;
    int*   nvalid = wsi + NVALID_OFF;
    float* mpart  = wsf + MPART_OFF;
    float* spart  = wsf + SPART_OFF;
    float* dlbl   = wsf + DLBL_OFF;

    hipMemsetAsync(d_ws, 0, (size_t)ZERO_WORDS * 4, stream);
    k_prep   <<<(Bn*Rn*Dn)/(256*8), 256, 0, stream>>>(inputs, cls, roi, xbf, counts);
    k_compact<<<Bn, 1024, 0, stream>>>(roi, counts, nuniq, cmap, ccnt, cursor, rlist, nvalid);
    k_proto  <<<Bn*MAXU, 64, 0, stream>>>(inputs, cls, nuniq, ccnt, cursor, rlist, pbf);
    dim3 g(Rn / TRr, 4, Bn);
    k_loss   <<<g, 256, 0, stream>>>(xbf, pbf, roi, cmap, nuniq, mpart, spart, dlbl);
    k_merge  <<<(Bn*Rn)/256, 256, 0, stream>>>(roi, nuniq, mpart, spart, dlbl, nll,
                                               ticket, nvalid, out);
}